// Round 9
// baseline (426.063 us; speedup 1.0000x reference)
//
#include <hip/hip_runtime.h>
#include <math.h>

#define NPTS 65536
#define NV 6890
#define NT 432               // vertex tiles of 16 (432*16 = 6912 >= 6890)
#define NTPAD 8              // sentinel tiles appended for unclamped prefetch
#define VSPLIT 8             // waves per block, splitting the vertex range
#define TILES_PER_WAVE (NT / VSPLIT)   // 54
#define NJ 24
#define PTS_PER_BLK 64       // 64 points per block; each wave computes all 64
#define NBLK (NPTS / PTS_PER_BLK)      // 1024

typedef double f64x4 __attribute__((ext_vector_type(4)));

// Prep: pack the B-fragment stream for v_mfma_f64_16x16x4_f64.
// frag[t*64 + l] = component (l>>4) of vertex (t*16 + (l&15));
// components: 0..2 = x,y,z (f64), 3 = ||v||^2 (exact f64 from f32 coords).
// Sentinel verts (j >= NV, incl. pad tiles): (0,0,0,1e300) -> never selected.
__global__ void prep_frags_k(const float* __restrict__ verts, double* __restrict__ bf) {
    int e = blockIdx.x * blockDim.x + threadIdx.x;
    if (e >= (NT + NTPAD) * 64) return;
    int l = e & 63;
    int t = e >> 6;
    int j = t * 16 + (l & 15);
    int k = l >> 4;
    double val;
    if (j < NV) {
        if (k < 3) {
            val = (double)verts[3 * j + k];
        } else {
            double x = (double)verts[3 * j + 0];
            double y = (double)verts[3 * j + 1];
            double z = (double)verts[3 * j + 2];
            val = x * x + y * y + z * z;
        }
    } else {
        val = (k == 3) ? 1e300 : 0.0;
    }
    bf[e] = val;
}

// Pack a 13-bit global vertex index (tile<<4 | col) into the low mantissa
// bits of the f64 score. Perturbation <= 2^13 ulp (~1e-12 rel) << NN gap
// (~1e-3): ordering-safe. Min of packed values == packed min, and exact
// ties resolve to the smallest vertex index (numpy first-occurrence).
__device__ __forceinline__ double packdx(double d, unsigned orv) {
    unsigned long long u = __double_as_longlong(d);
    u = (u & ~0x1FFFULL) | (unsigned long long)orv;
    return __longlong_as_double(u);
}

__launch_bounds__(512, 8)
__global__ void smplnn_main(const float* __restrict__ xyz,
                            const float* __restrict__ rot,
                            const double* __restrict__ bf,
                            const float* __restrict__ sw,
                            const float* __restrict__ bt,
                            float* __restrict__ out) {
    // column-reduced packed scores: [wave][point-in-block]
    __shared__ double smin2[VSPLIT][PTS_PER_BLK];

    const int tid  = threadIdx.x;
    const int lane = tid & 63;
    const int wave = tid >> 6;         // vertex-split id (0..7)
    const int r = lane & 15;           // M/N index within fragment
    const int k = lane >> 4;           // K index (0..3)
    const int pbase = blockIdx.x * PTS_PER_BLK;

    // A fragments: 4 groups of 16 points (same 64 points for all 8 waves).
    // A[i][k] = (-2x_i, -2y_i, -2z_i, 1.0), i = lane&15
    double a0 = (k == 3) ? 1.0 : -2.0 * (double)xyz[3 * (pbase +      r) + k];
    double a1 = (k == 3) ? 1.0 : -2.0 * (double)xyz[3 * (pbase + 16 + r) + k];
    double a2 = (k == 3) ? 1.0 : -2.0 * (double)xyz[3 * (pbase + 32 + r) + k];
    double a3 = (k == 3) ? 1.0 : -2.0 * (double)xyz[3 * (pbase + 48 + r) + k];

    const f64x4 zero = {0.0, 0.0, 0.0, 0.0};

    // Layout self-calibration: D = row-index and D = col-index, so the
    // (lane,reg)->(row,col) mapping of the D fragment never has to be assumed.
    double ar  = (k == 3) ? (double)r : 0.0;  // A[i][3] = i  /  B[3][j] = j
    double one = (k == 3) ? 1.0 : 0.0;        // A[i][3] = 1  /  B[3][j] = 1
    f64x4 drow = __builtin_amdgcn_mfma_f64_16x16x4f64(ar, one, zero, 0, 0, 0);
    f64x4 dcol = __builtin_amdgcn_mfma_f64_16x16x4f64(one, ar, zero, 0, 0, 0);
    int rowid[4];
    unsigned colb[4];
    #pragma unroll
    for (int v = 0; v < 4; ++v) { rowid[v] = (int)drow[v]; colb[v] = (unsigned)(int)dcol[v]; }

    double m0[4], m1[4], m2[4], m3[4];
    #pragma unroll
    for (int v = 0; v < 4; ++v) { m0[v] = 1e301; m1[v] = 1e301; m2[v] = 1e301; m3[v] = 1e301; }

    // scan my eighth of the tiles: s = -2 x.v + ||v||^2, exact f64 MFMA.
    // single-depth prefetch; latency hiding comes from 8 waves/SIMD TLP.
    const int tbase = wave * TILES_PER_WAVE;
    const double* bl = bf + (size_t)tbase * 64 + lane;
    double b = bl[0];
    for (int t = 0; t < TILES_PER_WAVE; ++t) {
        double p = bl[(size_t)(t + 1) * 64];   // pad tiles are sentinels
        const unsigned tb = (unsigned)((tbase + t) << 4);
        f64x4 d0 = __builtin_amdgcn_mfma_f64_16x16x4f64(a0, b, zero, 0, 0, 0);
        f64x4 d1 = __builtin_amdgcn_mfma_f64_16x16x4f64(a1, b, zero, 0, 0, 0);
        f64x4 d2 = __builtin_amdgcn_mfma_f64_16x16x4f64(a2, b, zero, 0, 0, 0);
        f64x4 d3 = __builtin_amdgcn_mfma_f64_16x16x4f64(a3, b, zero, 0, 0, 0);
        #pragma unroll
        for (int v = 0; v < 4; ++v) {
            const unsigned orv = tb | colb[v];
            m0[v] = fmin(m0[v], packdx(d0[v], orv));
            m1[v] = fmin(m1[v], packdx(d1[v], orv));
            m2[v] = fmin(m2[v], packdx(d2[v], orv));
            m3[v] = fmin(m3[v], packdx(d3[v], orv));
        }
        b = p;
    }

    // in-wave column reduction: butterfly over the 16 column-lanes.
    // After this every lane in a 16-lane group holds, for each (frag,v),
    // the min over all 16 columns of row rowid[v] (packed with its index).
    #pragma unroll
    for (int s = 1; s < 16; s <<= 1) {
        #pragma unroll
        for (int v = 0; v < 4; ++v) {
            m0[v] = fmin(m0[v], __shfl_xor(m0[v], s, 16));
            m1[v] = fmin(m1[v], __shfl_xor(m1[v], s, 16));
            m2[v] = fmin(m2[v], __shfl_xor(m2[v], s, 16));
            m3[v] = fmin(m3[v], __shfl_xor(m3[v], s, 16));
        }
    }

    // publish: 16 writer-lanes per group, one (frag,v) each.
    {
        const int sub = lane & 15;
        const int f = sub >> 2;
        const int v = sub & 3;
        double val = (f == 0) ? m0[v] : (f == 1) ? m1[v] : (f == 2) ? m2[v] : m3[v];
        // rowid[v] is group-uniform; distinct (f,rowid[v]) per writer.
        smin2[wave][f * 16 + rowid[v]] = val;
    }
    __syncthreads();

    // epilogue: wave 0, 64 lanes = 64 points
    if (wave != 0) return;
    const int i = pbase + lane;

    double best = smin2[0][lane];
    #pragma unroll
    for (int w = 1; w < VSPLIT; ++w) best = fmin(best, smin2[w][lane]);
    const int bi = (int)(__double_as_longlong(best) & 0x1FFFULL);  // tile*16+col

    const float xf = xyz[3 * i + 0];
    const float yf = xyz[3 * i + 1];
    const float zf = xyz[3 * i + 2];

    // T_fwd = W[bi] @ bone_transforms(24x16)
    const float* W = &sw[bi * NJ];
    float Tm[16];
    #pragma unroll
    for (int q = 0; q < 16; ++q) Tm[q] = 0.0f;
    #pragma unroll
    for (int kk = 0; kk < NJ; ++kk) {
        float w = W[kk];
        #pragma unroll
        for (int q = 0; q < 16; ++q) Tm[q] = fmaf(w, bt[16 * kk + q], Tm[q]);
    }

    // x_bar = T[:3,:3] @ x + T[:3,3]
    float xb0 = Tm[0] * xf + Tm[1] * yf + Tm[2]  * zf + Tm[3];
    float xb1 = Tm[4] * xf + Tm[5] * yf + Tm[6]  * zf + Tm[7];
    float xb2 = Tm[8] * xf + Tm[9] * yf + Tm[10] * zf + Tm[11];

    // rotation_hat from quaternion (r,x,y,z), normalized
    float qr = rot[4 * i + 0];
    float qx = rot[4 * i + 1];
    float qy = rot[4 * i + 2];
    float qz = rot[4 * i + 3];
    float inv = 1.0f / sqrtf(qr * qr + qx * qx + qy * qy + qz * qz);
    qr *= inv; qx *= inv; qy *= inv; qz *= inv;

    float Rh[9];
    Rh[0] = 1.0f - 2.0f * (qy * qy + qz * qz);
    Rh[1] = 2.0f * (qx * qy - qr * qz);
    Rh[2] = 2.0f * (qx * qz + qr * qy);
    Rh[3] = 2.0f * (qx * qy + qr * qz);
    Rh[4] = 1.0f - 2.0f * (qx * qx + qz * qz);
    Rh[5] = 2.0f * (qy * qz - qr * qx);
    Rh[6] = 2.0f * (qx * qz - qr * qy);
    Rh[7] = 2.0f * (qy * qz + qr * qx);
    Rh[8] = 1.0f - 2.0f * (qx * qx + qy * qy);

    // rotation_bar = T[:3,:3] @ Rh
    float RB[9];
    #pragma unroll
    for (int rr = 0; rr < 3; ++rr) {
        #pragma unroll
        for (int cc = 0; cc < 3; ++cc) {
            RB[3 * rr + cc] = Tm[4 * rr + 0] * Rh[cc]
                            + Tm[4 * rr + 1] * Rh[3 + cc]
                            + Tm[4 * rr + 2] * Rh[6 + cc];
        }
    }

    // outputs: x_bar [NPTS*3] | rotation_bar [NPTS*9] | T_fwd [NPTS*16]
    out[3 * i + 0] = xb0;
    out[3 * i + 1] = xb1;
    out[3 * i + 2] = xb2;
    float* ob = out + 3 * NPTS + 9 * i;
    #pragma unroll
    for (int q = 0; q < 9; ++q) ob[q] = RB[q];
    float* ot = out + 12 * NPTS + 16 * i;
    #pragma unroll
    for (int q = 0; q < 16; ++q) ot[q] = Tm[q];
}

extern "C" void kernel_launch(void* const* d_in, const int* in_sizes, int n_in,
                              void* d_out, int out_size, void* d_ws, size_t ws_size,
                              hipStream_t stream) {
    const float* xyz   = (const float*)d_in[0];
    const float* rot   = (const float*)d_in[1];
    const float* verts = (const float*)d_in[2];
    const float* sw    = (const float*)d_in[3];
    const float* bt    = (const float*)d_in[4];
    float* out = (float*)d_out;

    double* bfrag = (double*)d_ws;   // (NT+NTPAD)*64 doubles = 225 KB
    prep_frags_k<<<((NT + NTPAD) * 64 + 255) / 256, 256, 0, stream>>>(verts, bfrag);
    smplnn_main<<<NBLK, 512, 0, stream>>>(xyz, rot, bfrag, sw, bt, out);
}

// Round 10
// 130.971 us; speedup vs baseline: 3.2531x; 3.2531x over previous
//
#include <hip/hip_runtime.h>
#include <math.h>

#define NPTS 65536
#define NV 6890
#define NT 432               // vertex tiles of 16 (432*16 = 6912 >= 6890)
#define NTPAD 8              // sentinel tiles appended for unclamped prefetch
#define VSPLIT 4             // waves per block, splitting the block's vertex range
#define NJ 24
#define PTS_PER_BLK 64       // 64 points per block; each wave computes all 64
#define NBLK (NPTS / PTS_PER_BLK)      // 1024
#define FRAG_DBL ((NT + NTPAD) * 64)   // doubles in the B-fragment stream

typedef double f64x4 __attribute__((ext_vector_type(4)));

// Prep: pack the B-fragment stream for v_mfma_f64_16x16x4_f64.
// frag[t*64 + l] = component (l>>4) of vertex (t*16 + (l&15));
// components: 0..2 = x,y,z (f64), 3 = ||v||^2 (exact f64 from f32 coords).
// Sentinel verts (j >= NV, incl. pad tiles): (0,0,0,1e300) -> never selected.
__global__ void prep_frags_k(const float* __restrict__ verts, double* __restrict__ bf) {
    int e = blockIdx.x * blockDim.x + threadIdx.x;
    if (e >= FRAG_DBL) return;
    int l = e & 63;
    int t = e >> 6;
    int j = t * 16 + (l & 15);
    int k = l >> 4;
    double val;
    if (j < NV) {
        if (k < 3) {
            val = (double)verts[3 * j + k];
        } else {
            double x = (double)verts[3 * j + 0];
            double y = (double)verts[3 * j + 1];
            double z = (double)verts[3 * j + 2];
            val = x * x + y * y + z * z;
        }
    } else {
        val = (k == 3) ? 1e300 : 0.0;
    }
    bf[e] = val;
}

// Pack a 13-bit global vertex index (tile<<4 | col) into the low mantissa
// bits of the f64 score. Perturbation <= 2^13 ulp (~1e-12 rel) << NN gap
// (~1e-3): ordering-safe. Min of packed values == packed min, and exact
// ties resolve to the smallest vertex index (numpy first-occurrence).
__device__ __forceinline__ double packdx(double d, unsigned orv) {
    unsigned long long u = __double_as_longlong(d);
    u = (u & ~0x1FFFULL) | (unsigned long long)orv;
    return __longlong_as_double(u);
}

// Shared epilogue: given point i and its NN vertex bi, compute all outputs.
__device__ __forceinline__ void epilogue(int i, int bi,
                                         const float* __restrict__ xyz,
                                         const float* __restrict__ rot,
                                         const float* __restrict__ sw,
                                         const float* __restrict__ bt,
                                         float* __restrict__ out) {
    const float xf = xyz[3 * i + 0];
    const float yf = xyz[3 * i + 1];
    const float zf = xyz[3 * i + 2];

    // T_fwd = W[bi] @ bone_transforms(24x16)
    const float* W = &sw[bi * NJ];
    float Tm[16];
    #pragma unroll
    for (int q = 0; q < 16; ++q) Tm[q] = 0.0f;
    #pragma unroll
    for (int kk = 0; kk < NJ; ++kk) {
        float w = W[kk];
        #pragma unroll
        for (int q = 0; q < 16; ++q) Tm[q] = fmaf(w, bt[16 * kk + q], Tm[q]);
    }

    // x_bar = T[:3,:3] @ x + T[:3,3]
    float xb0 = Tm[0] * xf + Tm[1] * yf + Tm[2]  * zf + Tm[3];
    float xb1 = Tm[4] * xf + Tm[5] * yf + Tm[6]  * zf + Tm[7];
    float xb2 = Tm[8] * xf + Tm[9] * yf + Tm[10] * zf + Tm[11];

    // rotation_hat from quaternion (r,x,y,z), normalized
    float qr = rot[4 * i + 0];
    float qx = rot[4 * i + 1];
    float qy = rot[4 * i + 2];
    float qz = rot[4 * i + 3];
    float inv = 1.0f / sqrtf(qr * qr + qx * qx + qy * qy + qz * qz);
    qr *= inv; qx *= inv; qy *= inv; qz *= inv;

    float Rh[9];
    Rh[0] = 1.0f - 2.0f * (qy * qy + qz * qz);
    Rh[1] = 2.0f * (qx * qy - qr * qz);
    Rh[2] = 2.0f * (qx * qz + qr * qy);
    Rh[3] = 2.0f * (qx * qy + qr * qz);
    Rh[4] = 1.0f - 2.0f * (qx * qx + qz * qz);
    Rh[5] = 2.0f * (qy * qz - qr * qx);
    Rh[6] = 2.0f * (qx * qz - qr * qy);
    Rh[7] = 2.0f * (qy * qz + qr * qx);
    Rh[8] = 1.0f - 2.0f * (qx * qx + qy * qy);

    // rotation_bar = T[:3,:3] @ Rh
    float RB[9];
    #pragma unroll
    for (int rr = 0; rr < 3; ++rr) {
        #pragma unroll
        for (int cc = 0; cc < 3; ++cc) {
            RB[3 * rr + cc] = Tm[4 * rr + 0] * Rh[cc]
                            + Tm[4 * rr + 1] * Rh[3 + cc]
                            + Tm[4 * rr + 2] * Rh[6 + cc];
        }
    }

    // outputs: x_bar [NPTS*3] | rotation_bar [NPTS*9] | T_fwd [NPTS*16]
    out[3 * i + 0] = xb0;
    out[3 * i + 1] = xb1;
    out[3 * i + 2] = xb2;
    float* ob = out + 3 * NPTS + 9 * i;
    #pragma unroll
    for (int q = 0; q < 9; ++q) ob[q] = RB[q];
    float* ot = out + 12 * NPTS + 16 * i;
    #pragma unroll
    for (int q = 0; q < 16; ++q) ot[q] = Tm[q];
}

// Pass 1 (GSPLIT groups along blockIdx.y). GSPLIT==1: also runs the epilogue
// (single-pass fallback, identical to the round-8 kernel). GSPLIT>1: writes
// the block's 64 packed mins to pmin[gy*NPTS + point].
template <int GSPLIT>
__launch_bounds__(256)
__global__ void smplnn_scan(const float* __restrict__ xyz,
                            const float* __restrict__ rot,
                            const double* __restrict__ bf,
                            const float* __restrict__ sw,
                            const float* __restrict__ bt,
                            double* __restrict__ pmin,
                            float* __restrict__ out) {
    constexpr int TPW = NT / (VSPLIT * GSPLIT);   // tiles per wave
    __shared__ double smin2[VSPLIT][PTS_PER_BLK];

    const int tid  = threadIdx.x;
    const int lane = tid & 63;
    const int wave = tid >> 6;         // vertex-split id within block (0..3)
    const int r = lane & 15;           // M/N index within fragment
    const int k = lane >> 4;           // K index (0..3)
    const int pbase = blockIdx.x * PTS_PER_BLK;

    // A fragments: 4 groups of 16 points (same 64 points for all waves).
    // A[i][k] = (-2x_i, -2y_i, -2z_i, 1.0), i = lane&15
    double a0 = (k == 3) ? 1.0 : -2.0 * (double)xyz[3 * (pbase +      r) + k];
    double a1 = (k == 3) ? 1.0 : -2.0 * (double)xyz[3 * (pbase + 16 + r) + k];
    double a2 = (k == 3) ? 1.0 : -2.0 * (double)xyz[3 * (pbase + 32 + r) + k];
    double a3 = (k == 3) ? 1.0 : -2.0 * (double)xyz[3 * (pbase + 48 + r) + k];

    const f64x4 zero = {0.0, 0.0, 0.0, 0.0};

    // Layout self-calibration: D = row-index and D = col-index, so the
    // (lane,reg)->(row,col) mapping of the D fragment never has to be assumed.
    double ar  = (k == 3) ? (double)r : 0.0;  // A[i][3] = i  /  B[3][j] = j
    double one = (k == 3) ? 1.0 : 0.0;        // A[i][3] = 1  /  B[3][j] = 1
    f64x4 drow = __builtin_amdgcn_mfma_f64_16x16x4f64(ar, one, zero, 0, 0, 0);
    f64x4 dcol = __builtin_amdgcn_mfma_f64_16x16x4f64(one, ar, zero, 0, 0, 0);
    int rowid[4];
    unsigned colb[4];
    #pragma unroll
    for (int v = 0; v < 4; ++v) { rowid[v] = (int)drow[v]; colb[v] = (unsigned)(int)dcol[v]; }

    double m0[4], m1[4], m2[4], m3[4];
    #pragma unroll
    for (int v = 0; v < 4; ++v) { m0[v] = 1e301; m1[v] = 1e301; m2[v] = 1e301; m3[v] = 1e301; }

    // scan my share of the tiles: s = -2 x.v + ||v||^2, exact f64 MFMA.
    // 2-tile-deep software pipeline.
    const int tbase = (blockIdx.y * VSPLIT + wave) * TPW;
    const double* bl = bf + (size_t)tbase * 64 + lane;
    double b0 = bl[0];
    double b1 = bl[64];
    for (int t = 0; t < TPW; t += 2) {
        double p0 = bl[(size_t)(t + 2) * 64];   // pad tiles are sentinels
        double p1 = bl[(size_t)(t + 3) * 64];
        {
            const unsigned tb = (unsigned)((tbase + t) << 4);
            f64x4 d0 = __builtin_amdgcn_mfma_f64_16x16x4f64(a0, b0, zero, 0, 0, 0);
            f64x4 d1 = __builtin_amdgcn_mfma_f64_16x16x4f64(a1, b0, zero, 0, 0, 0);
            f64x4 d2 = __builtin_amdgcn_mfma_f64_16x16x4f64(a2, b0, zero, 0, 0, 0);
            f64x4 d3 = __builtin_amdgcn_mfma_f64_16x16x4f64(a3, b0, zero, 0, 0, 0);
            #pragma unroll
            for (int v = 0; v < 4; ++v) {
                const unsigned orv = tb | colb[v];
                m0[v] = fmin(m0[v], packdx(d0[v], orv));
                m1[v] = fmin(m1[v], packdx(d1[v], orv));
                m2[v] = fmin(m2[v], packdx(d2[v], orv));
                m3[v] = fmin(m3[v], packdx(d3[v], orv));
            }
        }
        {
            const unsigned tb = (unsigned)((tbase + t + 1) << 4);
            f64x4 d0 = __builtin_amdgcn_mfma_f64_16x16x4f64(a0, b1, zero, 0, 0, 0);
            f64x4 d1 = __builtin_amdgcn_mfma_f64_16x16x4f64(a1, b1, zero, 0, 0, 0);
            f64x4 d2 = __builtin_amdgcn_mfma_f64_16x16x4f64(a2, b1, zero, 0, 0, 0);
            f64x4 d3 = __builtin_amdgcn_mfma_f64_16x16x4f64(a3, b1, zero, 0, 0, 0);
            #pragma unroll
            for (int v = 0; v < 4; ++v) {
                const unsigned orv = tb | colb[v];
                m0[v] = fmin(m0[v], packdx(d0[v], orv));
                m1[v] = fmin(m1[v], packdx(d1[v], orv));
                m2[v] = fmin(m2[v], packdx(d2[v], orv));
                m3[v] = fmin(m3[v], packdx(d3[v], orv));
            }
        }
        b0 = p0;
        b1 = p1;
    }

    // in-wave column reduction: butterfly over the 16 column-lanes.
    #pragma unroll
    for (int s = 1; s < 16; s <<= 1) {
        #pragma unroll
        for (int v = 0; v < 4; ++v) {
            m0[v] = fmin(m0[v], __shfl_xor(m0[v], s, 16));
            m1[v] = fmin(m1[v], __shfl_xor(m1[v], s, 16));
            m2[v] = fmin(m2[v], __shfl_xor(m2[v], s, 16));
            m3[v] = fmin(m3[v], __shfl_xor(m3[v], s, 16));
        }
    }

    // publish: 16 writer-lanes per group, one (frag,v) each.
    {
        const int sub = lane & 15;
        const int f = sub >> 2;
        const int v = sub & 3;
        double val = (f == 0) ? m0[v] : (f == 1) ? m1[v] : (f == 2) ? m2[v] : m3[v];
        smin2[wave][f * 16 + rowid[v]] = val;   // rowid[v] is group-uniform
    }
    __syncthreads();

    if (wave != 0) return;

    double best = smin2[0][lane];
    #pragma unroll
    for (int w = 1; w < VSPLIT; ++w) best = fmin(best, smin2[w][lane]);

    if (GSPLIT > 1) {
        pmin[blockIdx.y * NPTS + pbase + lane] = best;
    } else {
        const int bi = (int)(__double_as_longlong(best) & 0x1FFFULL);
        epilogue(pbase + lane, bi, xyz, rot, sw, bt, out);
    }
}

// Pass 2: merge the GSPLIT packed mins per point, run the epilogue.
__launch_bounds__(256)
__global__ void smplnn_merge(const double* __restrict__ pmin,
                             const float* __restrict__ xyz,
                             const float* __restrict__ rot,
                             const float* __restrict__ sw,
                             const float* __restrict__ bt,
                             float* __restrict__ out) {
    const int i = blockIdx.x * blockDim.x + threadIdx.x;
    double best = fmin(pmin[i], pmin[NPTS + i]);
    const int bi = (int)(__double_as_longlong(best) & 0x1FFFULL);
    epilogue(i, bi, xyz, rot, sw, bt, out);
}

extern "C" void kernel_launch(void* const* d_in, const int* in_sizes, int n_in,
                              void* d_out, int out_size, void* d_ws, size_t ws_size,
                              hipStream_t stream) {
    const float* xyz   = (const float*)d_in[0];
    const float* rot   = (const float*)d_in[1];
    const float* verts = (const float*)d_in[2];
    const float* sw    = (const float*)d_in[3];
    const float* bt    = (const float*)d_in[4];
    float* out = (float*)d_out;

    double* bfrag = (double*)d_ws;                 // 225,280 B
    double* pmin  = bfrag + FRAG_DBL;              // 2 * NPTS * 8 B = 1 MiB

    prep_frags_k<<<(FRAG_DBL + 255) / 256, 256, 0, stream>>>(verts, bfrag);

    const size_t need = (size_t)FRAG_DBL * 8 + (size_t)2 * NPTS * 8;
    if (ws_size >= need) {
        dim3 grid(NBLK, 2);
        smplnn_scan<2><<<grid, 256, 0, stream>>>(xyz, rot, bfrag, sw, bt, pmin, out);
        smplnn_merge<<<NPTS / 256, 256, 0, stream>>>(pmin, xyz, rot, sw, bt, out);
    } else {
        smplnn_scan<1><<<dim3(NBLK, 1), 256, 0, stream>>>(xyz, rot, bfrag, sw, bt, nullptr, out);
    }
}

// Round 11
// 115.927 us; speedup vs baseline: 3.6753x; 1.1298x over previous
//
#include <hip/hip_runtime.h>
#include <math.h>

#define NPTS 65536
#define NV 6890
#define NT 432               // vertex tiles of 16 (432*16 = 6912 >= 6890)
#define NTPAD 8              // sentinel tiles appended for unclamped prefetch
#define VSPLIT 4             // waves per block, splitting the block's vertex range
#define NJ 24
#define PTS_PER_BLK 64       // 64 points per block; each wave computes all 64
#define NBLK (NPTS / PTS_PER_BLK)      // 1024
#define FRAG_DBL ((NT + NTPAD) * 64)   // doubles in the B-fragment stream

typedef double f64x4 __attribute__((ext_vector_type(4)));

// Prep: pack the B-fragment stream for v_mfma_f64_16x16x4_f64.
// frag[t*64 + l] = component (l>>4) of vertex (t*16 + (l&15));
// components: 0..2 = x,y,z (f64), 3 = ||v||^2 (exact f64 from f32 coords).
// Sentinel verts (j >= NV, incl. pad tiles): (0,0,0,1e300) -> never selected.
__global__ void prep_frags_k(const float* __restrict__ verts, double* __restrict__ bf) {
    int e = blockIdx.x * blockDim.x + threadIdx.x;
    if (e >= FRAG_DBL) return;
    int l = e & 63;
    int t = e >> 6;
    int j = t * 16 + (l & 15);
    int k = l >> 4;
    double val;
    if (j < NV) {
        if (k < 3) {
            val = (double)verts[3 * j + k];
        } else {
            double x = (double)verts[3 * j + 0];
            double y = (double)verts[3 * j + 1];
            double z = (double)verts[3 * j + 2];
            val = x * x + y * y + z * z;
        }
    } else {
        val = (k == 3) ? 1e300 : 0.0;
    }
    bf[e] = val;
}

// m = min(m, d with low-13 mantissa bits replaced by orv).
// Index pack: perturbation <= 2^13 ulp (~1e-12 rel) << NN gap (~1e-3):
// ordering-safe (same class as rounds 6-10, absmax bit-stable).
// Inline-asm v_min_f64 bypasses LLVM's IEEE canonicalization (v_max_f64 x,x
// quieting on both inputs) that triples the cost of fmin(double).
__device__ __forceinline__ void packmin(double& m, double d, unsigned orv) {
    unsigned long long u = __double_as_longlong(d);
    u = (u & ~0x1FFFULL) | (unsigned long long)orv;   // hi word untouched
    double t = __longlong_as_double(u);
    asm("v_min_f64 %0, %0, %1" : "+v"(m) : "v"(t));
}

// Shared epilogue: given point i and its NN vertex bi, compute all outputs.
__device__ __forceinline__ void epilogue(int i, int bi,
                                         const float* __restrict__ xyz,
                                         const float* __restrict__ rot,
                                         const float* __restrict__ sw,
                                         const float* __restrict__ bt,
                                         float* __restrict__ out) {
    const float xf = xyz[3 * i + 0];
    const float yf = xyz[3 * i + 1];
    const float zf = xyz[3 * i + 2];

    // T_fwd = W[bi] @ bone_transforms(24x16)
    const float* W = &sw[bi * NJ];
    float Tm[16];
    #pragma unroll
    for (int q = 0; q < 16; ++q) Tm[q] = 0.0f;
    #pragma unroll
    for (int kk = 0; kk < NJ; ++kk) {
        float w = W[kk];
        #pragma unroll
        for (int q = 0; q < 16; ++q) Tm[q] = fmaf(w, bt[16 * kk + q], Tm[q]);
    }

    // x_bar = T[:3,:3] @ x + T[:3,3]
    float xb0 = Tm[0] * xf + Tm[1] * yf + Tm[2]  * zf + Tm[3];
    float xb1 = Tm[4] * xf + Tm[5] * yf + Tm[6]  * zf + Tm[7];
    float xb2 = Tm[8] * xf + Tm[9] * yf + Tm[10] * zf + Tm[11];

    // rotation_hat from quaternion (r,x,y,z), normalized
    float qr = rot[4 * i + 0];
    float qx = rot[4 * i + 1];
    float qy = rot[4 * i + 2];
    float qz = rot[4 * i + 3];
    float inv = 1.0f / sqrtf(qr * qr + qx * qx + qy * qy + qz * qz);
    qr *= inv; qx *= inv; qy *= inv; qz *= inv;

    float Rh[9];
    Rh[0] = 1.0f - 2.0f * (qy * qy + qz * qz);
    Rh[1] = 2.0f * (qx * qy - qr * qz);
    Rh[2] = 2.0f * (qx * qz + qr * qy);
    Rh[3] = 2.0f * (qx * qy + qr * qz);
    Rh[4] = 1.0f - 2.0f * (qx * qx + qz * qz);
    Rh[5] = 2.0f * (qy * qz - qr * qx);
    Rh[6] = 2.0f * (qx * qz - qr * qy);
    Rh[7] = 2.0f * (qy * qz + qr * qx);
    Rh[8] = 1.0f - 2.0f * (qx * qx + qy * qy);

    // rotation_bar = T[:3,:3] @ Rh
    float RB[9];
    #pragma unroll
    for (int rr = 0; rr < 3; ++rr) {
        #pragma unroll
        for (int cc = 0; cc < 3; ++cc) {
            RB[3 * rr + cc] = Tm[4 * rr + 0] * Rh[cc]
                            + Tm[4 * rr + 1] * Rh[3 + cc]
                            + Tm[4 * rr + 2] * Rh[6 + cc];
        }
    }

    // outputs: x_bar [NPTS*3] | rotation_bar [NPTS*9] | T_fwd [NPTS*16]
    out[3 * i + 0] = xb0;
    out[3 * i + 1] = xb1;
    out[3 * i + 2] = xb2;
    float* ob = out + 3 * NPTS + 9 * i;
    #pragma unroll
    for (int q = 0; q < 9; ++q) ob[q] = RB[q];
    float* ot = out + 12 * NPTS + 16 * i;
    #pragma unroll
    for (int q = 0; q < 16; ++q) ot[q] = Tm[q];
}

// Pass 1 (GSPLIT groups along blockIdx.y). GSPLIT==1: also runs the epilogue
// (single-pass fallback). GSPLIT>1: writes the block's 64 packed mins to
// pmin[gy*NPTS + point].
template <int GSPLIT>
__launch_bounds__(256)
__global__ void smplnn_scan(const float* __restrict__ xyz,
                            const float* __restrict__ rot,
                            const double* __restrict__ bf,
                            const float* __restrict__ sw,
                            const float* __restrict__ bt,
                            double* __restrict__ pmin,
                            float* __restrict__ out) {
    constexpr int TPW = NT / (VSPLIT * GSPLIT);   // tiles per wave (54 / 108)
    __shared__ double smin2[VSPLIT][PTS_PER_BLK];

    const int tid  = threadIdx.x;
    const int lane = tid & 63;
    const int wave = tid >> 6;         // vertex-split id within block (0..3)
    const int r = lane & 15;           // M/N index within fragment
    const int k = lane >> 4;           // K index (0..3)
    const int pbase = blockIdx.x * PTS_PER_BLK;

    // A fragments: 4 groups of 16 points (same 64 points for all waves).
    // A[i][k] = (-2x_i, -2y_i, -2z_i, 1.0), i = lane&15
    double a0 = (k == 3) ? 1.0 : -2.0 * (double)xyz[3 * (pbase +      r) + k];
    double a1 = (k == 3) ? 1.0 : -2.0 * (double)xyz[3 * (pbase + 16 + r) + k];
    double a2 = (k == 3) ? 1.0 : -2.0 * (double)xyz[3 * (pbase + 32 + r) + k];
    double a3 = (k == 3) ? 1.0 : -2.0 * (double)xyz[3 * (pbase + 48 + r) + k];

    const f64x4 zero = {0.0, 0.0, 0.0, 0.0};

    // Layout self-calibration: D = row-index and D = col-index, so the
    // (lane,reg)->(row,col) mapping of the D fragment never has to be assumed.
    double ar  = (k == 3) ? (double)r : 0.0;  // A[i][3] = i  /  B[3][j] = j
    double one = (k == 3) ? 1.0 : 0.0;        // A[i][3] = 1  /  B[3][j] = 1
    f64x4 drow = __builtin_amdgcn_mfma_f64_16x16x4f64(ar, one, zero, 0, 0, 0);
    f64x4 dcol = __builtin_amdgcn_mfma_f64_16x16x4f64(one, ar, zero, 0, 0, 0);
    int rowid[4];
    unsigned colb[4];
    #pragma unroll
    for (int v = 0; v < 4; ++v) { rowid[v] = (int)drow[v]; colb[v] = (unsigned)(int)dcol[v]; }

    double m0[4], m1[4], m2[4], m3[4];
    #pragma unroll
    for (int v = 0; v < 4; ++v) { m0[v] = 1e301; m1[v] = 1e301; m2[v] = 1e301; m3[v] = 1e301; }

    // scan my share of the tiles: s = -2 x.v + ||v||^2, exact f64 MFMA.
    // 2-tile software pipeline; pointer-bump addressing with imm offsets.
    const int tbase = (blockIdx.y * VSPLIT + wave) * TPW;
    const double* bp = bf + (size_t)tbase * 64 + lane;
    double b0 = bp[0];
    double b1 = bp[64];
    unsigned tb = (unsigned)(tbase << 4);
    for (int t = 0; t < TPW; t += 2) {
        double p0 = bp[128];               // folds to offset:1024
        double p1 = bp[192];               // folds to offset:1536
        bp += 128;
        {
            f64x4 d0 = __builtin_amdgcn_mfma_f64_16x16x4f64(a0, b0, zero, 0, 0, 0);
            f64x4 d1 = __builtin_amdgcn_mfma_f64_16x16x4f64(a1, b0, zero, 0, 0, 0);
            f64x4 d2 = __builtin_amdgcn_mfma_f64_16x16x4f64(a2, b0, zero, 0, 0, 0);
            f64x4 d3 = __builtin_amdgcn_mfma_f64_16x16x4f64(a3, b0, zero, 0, 0, 0);
            unsigned o0 = tb | colb[0];
            unsigned o1 = tb | colb[1];
            unsigned o2 = tb | colb[2];
            unsigned o3 = tb | colb[3];
            packmin(m0[0], d0[0], o0); packmin(m0[1], d0[1], o1);
            packmin(m0[2], d0[2], o2); packmin(m0[3], d0[3], o3);
            packmin(m1[0], d1[0], o0); packmin(m1[1], d1[1], o1);
            packmin(m1[2], d1[2], o2); packmin(m1[3], d1[3], o3);
            packmin(m2[0], d2[0], o0); packmin(m2[1], d2[1], o1);
            packmin(m2[2], d2[2], o2); packmin(m2[3], d2[3], o3);
            packmin(m3[0], d3[0], o0); packmin(m3[1], d3[1], o1);
            packmin(m3[2], d3[2], o2); packmin(m3[3], d3[3], o3);
        }
        tb += 16;
        {
            f64x4 d0 = __builtin_amdgcn_mfma_f64_16x16x4f64(a0, b1, zero, 0, 0, 0);
            f64x4 d1 = __builtin_amdgcn_mfma_f64_16x16x4f64(a1, b1, zero, 0, 0, 0);
            f64x4 d2 = __builtin_amdgcn_mfma_f64_16x16x4f64(a2, b1, zero, 0, 0, 0);
            f64x4 d3 = __builtin_amdgcn_mfma_f64_16x16x4f64(a3, b1, zero, 0, 0, 0);
            unsigned o0 = tb | colb[0];
            unsigned o1 = tb | colb[1];
            unsigned o2 = tb | colb[2];
            unsigned o3 = tb | colb[3];
            packmin(m0[0], d0[0], o0); packmin(m0[1], d0[1], o1);
            packmin(m0[2], d0[2], o2); packmin(m0[3], d0[3], o3);
            packmin(m1[0], d1[0], o0); packmin(m1[1], d1[1], o1);
            packmin(m1[2], d1[2], o2); packmin(m1[3], d1[3], o3);
            packmin(m2[0], d2[0], o0); packmin(m2[1], d2[1], o1);
            packmin(m2[2], d2[2], o2); packmin(m2[3], d2[3], o3);
            packmin(m3[0], d3[0], o0); packmin(m3[1], d3[1], o1);
            packmin(m3[2], d3[2], o2); packmin(m3[3], d3[3], o3);
        }
        tb += 16;
        b0 = p0;
        b1 = p1;
    }

    // in-wave column reduction: butterfly over the 16 column-lanes.
    #pragma unroll
    for (int s = 1; s < 16; s <<= 1) {
        #pragma unroll
        for (int v = 0; v < 4; ++v) {
            m0[v] = fmin(m0[v], __shfl_xor(m0[v], s, 16));
            m1[v] = fmin(m1[v], __shfl_xor(m1[v], s, 16));
            m2[v] = fmin(m2[v], __shfl_xor(m2[v], s, 16));
            m3[v] = fmin(m3[v], __shfl_xor(m3[v], s, 16));
        }
    }

    // publish: 16 writer-lanes per group, one (frag,v) each.
    {
        const int sub = lane & 15;
        const int f = sub >> 2;
        const int v = sub & 3;
        double val = (f == 0) ? m0[v] : (f == 1) ? m1[v] : (f == 2) ? m2[v] : m3[v];
        smin2[wave][f * 16 + rowid[v]] = val;   // rowid[v] is group-uniform
    }
    __syncthreads();

    if (wave != 0) return;

    double best = smin2[0][lane];
    #pragma unroll
    for (int w = 1; w < VSPLIT; ++w) best = fmin(best, smin2[w][lane]);

    if (GSPLIT > 1) {
        pmin[blockIdx.y * NPTS + pbase + lane] = best;
    } else {
        const int bi = (int)(__double_as_longlong(best) & 0x1FFFULL);
        epilogue(pbase + lane, bi, xyz, rot, sw, bt, out);
    }
}

// Pass 2: merge the GSPLIT packed mins per point, run the epilogue.
__launch_bounds__(256)
__global__ void smplnn_merge(const double* __restrict__ pmin,
                             const float* __restrict__ xyz,
                             const float* __restrict__ rot,
                             const float* __restrict__ sw,
                             const float* __restrict__ bt,
                             float* __restrict__ out) {
    const int i = blockIdx.x * blockDim.x + threadIdx.x;
    double best = fmin(pmin[i], pmin[NPTS + i]);
    const int bi = (int)(__double_as_longlong(best) & 0x1FFFULL);
    epilogue(i, bi, xyz, rot, sw, bt, out);
}

extern "C" void kernel_launch(void* const* d_in, const int* in_sizes, int n_in,
                              void* d_out, int out_size, void* d_ws, size_t ws_size,
                              hipStream_t stream) {
    const float* xyz   = (const float*)d_in[0];
    const float* rot   = (const float*)d_in[1];
    const float* verts = (const float*)d_in[2];
    const float* sw    = (const float*)d_in[3];
    const float* bt    = (const float*)d_in[4];
    float* out = (float*)d_out;

    double* bfrag = (double*)d_ws;                 // 225,280 B
    double* pmin  = bfrag + FRAG_DBL;              // 2 * NPTS * 8 B = 1 MiB

    prep_frags_k<<<(FRAG_DBL + 255) / 256, 256, 0, stream>>>(verts, bfrag);

    const size_t need = (size_t)FRAG_DBL * 8 + (size_t)2 * NPTS * 8;
    if (ws_size >= need) {
        dim3 grid(NBLK, 2);
        smplnn_scan<2><<<grid, 256, 0, stream>>>(xyz, rot, bfrag, sw, bt, pmin, out);
        smplnn_merge<<<NPTS / 256, 256, 0, stream>>>(pmin, xyz, rot, sw, bt, out);
    } else {
        smplnn_scan<1><<<dim3(NBLK, 1), 256, 0, stream>>>(xyz, rot, bfrag, sw, bt, nullptr, out);
    }
}